// Round 1
// baseline (843.208 us; speedup 1.0000x reference)
//
#include <hip/hip_runtime.h>
#include <hip/hip_bf16.h>
#include <math.h>

#define EMBED_DIM 512
#define NUM_CLASSES 100000
#define NUM_SUB 3
#define BATCH 256
#define M_TOTAL (NUM_CLASSES*NUM_SUB)   // 300000
#define BM 96                            // weight rows per block = 32 whole classes
#define BK 64
#define LDB 72                           // padded bf16 stride for B tile (2-way banks = free)
#define NBLOCKS (M_TOTAL/BM)             // 3125

typedef float  floatx4 __attribute__((ext_vector_type(4)));
typedef __bf16 bf16x8  __attribute__((ext_vector_type(8)));

// round-to-nearest-even fp32 -> bf16 (bit trick)
__device__ __forceinline__ unsigned int f2bf(float f){
  unsigned int u = __float_as_uint(f);
  u += 0x7FFFu + ((u >> 16) & 1u);
  return u >> 16;
}

__device__ __forceinline__ void gload_lds16(const void* g, void* l){
  __builtin_amdgcn_global_load_lds(
      (const __attribute__((address_space(1))) unsigned int*)g,
      (__attribute__((address_space(3))) unsigned int*)l,
      16, 0, 0);
}

// ---------------- kernel 1: normalize embeddings, pack bf16, K-tile-major ----
// ehat layout: [kt=K/64][batch=256][64] bf16 -> each GEMM A-tile is one
// contiguous 32 KB chunk (global_load_lds friendly).
__global__ __launch_bounds__(64) void normalize_pack(
    const float* __restrict__ E, unsigned short* __restrict__ ehat)
{
  const int r    = blockIdx.x;     // batch row
  const int lane = threadIdx.x;    // 64 lanes, 8 floats each
  const float4 v0 = *(const float4*)(E + r*EMBED_DIM + lane*8);
  const float4 v1 = *(const float4*)(E + r*EMBED_DIM + lane*8 + 4);
  float ssq = v0.x*v0.x + v0.y*v0.y + v0.z*v0.z + v0.w*v0.w
            + v1.x*v1.x + v1.y*v1.y + v1.z*v1.z + v1.w*v1.w;
  #pragma unroll
  for (int m = 1; m < 64; m <<= 1) ssq += __shfl_xor(ssq, m, 64);
  float nn = sqrtf(ssq);
  nn = fmaxf(nn, 1e-12f);           // matches F.normalize eps semantics
  const float rn = 1.0f / nn;
  const float vals[8] = {v0.x, v0.y, v0.z, v0.w, v1.x, v1.y, v1.z, v1.w};
  unsigned int p[4];
  #pragma unroll
  for (int i = 0; i < 4; ++i)
    p[i] = f2bf(vals[2*i]*rn) | (f2bf(vals[2*i+1]*rn) << 16);
  const int kt = lane >> 3;                       // (lane*8)/64
  const size_t off = (size_t)kt*(BATCH*BK) + (size_t)r*BK + (lane & 7)*8;
  *(uint4*)(ehat + off) = make_uint4(p[0], p[1], p[2], p[3]);
}

// ---------------- kernel 2: fused GEMM + norm + subcenter-max + margin + exp --
__global__ __launch_bounds__(256, 2) void arcface_main(
    const float* __restrict__ W,            // [300000][512] fp32 row-major
    const unsigned short* __restrict__ ehat,// blocked bf16 (see above)
    const int* __restrict__ labels,
    float* __restrict__ gsum,               // [256] stride-16 fp32 accumulators
    float* __restrict__ llogit)             // [256] fp32, 64*phi at label class
{
  // LDS: staging A [256][64] bf16 (32768 B) + B [96][72] bf16 (13824 B)
  //      epilogue reuses the same region as 4 x [64][49] fp32 (50176 B)
  __shared__ char  smem[50176];
  __shared__ float snorm[BM];

  const int tid  = threadIdx.x;
  const int wave = tid >> 6, lane = tid & 63;
  const int m0   = blockIdx.x * BM;

  unsigned short* lA = (unsigned short*)smem;            // [256][64]
  unsigned short* lB = (unsigned short*)(smem + 32768);  // [96][LDB]

  floatx4 acc[24] = {};                 // wave: 4 row-tiles(batch) x 6 col-tiles(weight)
  float ssq_acc[6] = {0,0,0,0,0,0};
  const int r16 = tid >> 4, c4 = tid & 15;   // B staging: 16 threads per row

  for (int kt = 0; kt < 8; ++kt){
    // ---- stage A (async, direct-to-LDS, contiguous 1 KB per wave-issue) ----
    {
      const char* asrc = (const char*)ehat + kt*32768 + wave*8192 + lane*16;
      char*       adst = smem + wave*8192 + lane*16;
      #pragma unroll
      for (int i = 0; i < 8; ++i) gload_lds16(asrc + i*1024, adst + i*1024);
    }
    // ---- stage B: load fp32, accumulate row ssq, convert bf16, LDS write ----
    #pragma unroll
    for (int it = 0; it < 6; ++it){
      const int row = it*16 + r16;
      const float4 v = *(const float4*)(W + (size_t)(m0 + row)*EMBED_DIM + kt*BK + c4*4);
      ssq_acc[it] += v.x*v.x + v.y*v.y + v.z*v.z + v.w*v.w;
      const unsigned int p0 = f2bf(v.x) | (f2bf(v.y) << 16);
      const unsigned int p1 = f2bf(v.z) | (f2bf(v.w) << 16);
      *(uint2*)(lB + row*LDB + c4*4) = make_uint2(p0, p1);
    }
    __syncthreads();
    // ---- MFMA: D[batch][wrow]; A lane layout A[m=lane&15][k=quad*8+j] -------
    #pragma unroll
    for (int h = 0; h < 2; ++h){
      bf16x8 a[4], b[6];
      #pragma unroll
      for (int rt = 0; rt < 4; ++rt)
        a[rt] = *(const bf16x8*)(lA + (wave*64 + rt*16 + (lane & 15))*64 + h*32 + (lane >> 4)*8);
      #pragma unroll
      for (int ct = 0; ct < 6; ++ct)
        b[ct] = *(const bf16x8*)(lB + (ct*16 + (lane & 15))*LDB + h*32 + (lane >> 4)*8);
      #pragma unroll
      for (int rt = 0; rt < 4; ++rt)
        #pragma unroll
        for (int ct = 0; ct < 6; ++ct)
          acc[rt*6 + ct] = __builtin_amdgcn_mfma_f32_16x16x32_bf16(
              a[rt], b[ct], acc[rt*6 + ct], 0, 0, 0);
    }
    __syncthreads();
  }

  // ---- finalize per-row weight norms (16 staging lanes share a row) --------
  #pragma unroll
  for (int it = 0; it < 6; ++it){
    float s = ssq_acc[it];
    s += __shfl_xor(s, 1, 64); s += __shfl_xor(s, 2, 64);
    s += __shfl_xor(s, 4, 64); s += __shfl_xor(s, 8, 64);
    if (c4 == 0) snorm[it*16 + r16] = s;
  }
  __syncthreads();

  // ---- epilogue: cosine -> LDS -> subcenter max -> margin -> exp-sum -------
  const int col = lane & 15, quad = lane >> 4;
  float rnorm6[6];
  #pragma unroll
  for (int i = 0; i < 6; ++i){
    float nw = sqrtf(snorm[i*16 + col]);
    rnorm6[i] = 1.0f / fmaxf(nw, 1e-12f);
  }
  const int   nrow = wave*64 + lane;      // this lane's batch row in read phase
  const int   lbl  = labels[nrow];
  float*      ebuf = (float*)smem + wave*(64*49);
  float       contrib = 0.0f;
  const float cos_m = 0.87758256189037276f;
  const float sin_m = 0.47942553860420301f;
  const float thr   = -0.87758256189037276f;   // cos(pi - m)
  const float mmv   = 0.23971276930210156f;    // sin(pi - m)*m
  const int   cls0  = m0 / 3;

  #pragma unroll
  for (int half = 0; half < 2; ++half){
    // write 64 x 48 cosines (this wave's private 12.25 KB slice, stride 49)
    #pragma unroll
    for (int ct = 0; ct < 3; ++ct){
      const int ctg = half*3 + ct;
      #pragma unroll
      for (int rt = 0; rt < 4; ++rt)
        #pragma unroll
        for (int r = 0; r < 4; ++r)
          ebuf[(rt*16 + quad*4 + r)*49 + ct*16 + col] = acc[rt*6 + ctg][r] * rnorm6[ctg];
    }
    __syncthreads();
    // read phase: lane = batch row, 16 classes of 3 subcenters each
    for (int c = 0; c < 16; ++c){
      const float a0 = ebuf[lane*49 + 3*c + 0];
      const float a1 = ebuf[lane*49 + 3*c + 1];
      const float a2 = ebuf[lane*49 + 3*c + 2];
      float cm = fmaxf(a0, fmaxf(a1, a2));
      float val = cm;
      const int cls = cls0 + half*16 + c;
      if (cls == lbl){
        const float sine = sqrtf(fmaxf(0.0f, 1.0f - cm*cm));
        const float phi  = cm*cos_m - sine*sin_m;
        val = (cm > thr) ? phi : (cm - mmv);
        llogit[nrow] = 64.0f * val;
      }
      contrib += __expf(64.0f*val - 64.0f);   // logits <= 64 always -> safe shift
    }
    __syncthreads();
  }
  atomicAdd(&gsum[nrow*16], contrib);
}

// ---------------- kernel 3: loss = mean(log(sum) + 64 - label_logit) --------
__global__ __launch_bounds__(256) void finalize_loss(
    const float* __restrict__ gsum, const float* __restrict__ llogit,
    float* __restrict__ out)
{
  const int tid = threadIdx.x;
  float v = logf(gsum[tid*16]) + 64.0f - llogit[tid];
  #pragma unroll
  for (int m = 1; m < 64; m <<= 1) v += __shfl_xor(v, m, 64);
  __shared__ float red[4];
  if ((tid & 63) == 0) red[tid >> 6] = v;
  __syncthreads();
  if (tid == 0) out[0] = (red[0] + red[1] + red[2] + red[3]) * (1.0f/BATCH);
}

extern "C" void kernel_launch(void* const* d_in, const int* in_sizes, int n_in,
                              void* d_out, int out_size, void* d_ws, size_t ws_size,
                              hipStream_t stream)
{
  const float* emb    = (const float*)d_in[0];
  const int*   labels = (const int*)d_in[1];
  const float* W      = (const float*)d_in[2];

  // workspace layout: ehat bf16 blocked (262144 B) | gsum (16384 B) | llogit (1024 B)
  unsigned short* ehat   = (unsigned short*)d_ws;
  float*          gsum   = (float*)((char*)d_ws + 262144);
  float*          llogit = (float*)((char*)d_ws + 262144 + 16384);

  hipMemsetAsync(gsum, 0, 16384, stream);
  normalize_pack<<<BATCH, 64, 0, stream>>>(emb, ehat);
  arcface_main<<<NBLOCKS, 256, 0, stream>>>(W, ehat, labels, gsum, llogit);
  finalize_loss<<<1, 256, 0, stream>>>(gsum, llogit, (float*)d_out);
}